// Round 6
// baseline (11114.803 us; speedup 1.0000x reference)
//
#include <hip/hip_runtime.h>
#include <hip/hip_cooperative_groups.h>
#include <stdint.h>

namespace cg = cooperative_groups;

typedef unsigned short u16;
typedef __attribute__((ext_vector_type(8))) _Float16 f16x8;
typedef __attribute__((ext_vector_type(4))) float f32x4;

// ---------- helpers ----------
__device__ inline f16x8 ldfrag(const u16* p) { return *(const f16x8*)p; }
__device__ inline u16 f2h(float x) {
    _Float16 h = (_Float16)x;
    union { _Float16 h; u16 u; } v; v.h = h;
    return v.u;
}
__device__ inline float sigmoidf_(float x) { return 1.0f / (1.0f + expf(-x)); }

// Layouts (fp16 as u16):
//  A-frag (X: 256 x K):  AF[mtile][kb][lane][8]
//      = X[mtile*16 + (lane&15)][kb*32 + (lane>>4)*8 + j]
//  B-frag (W: N x K):    BF[grp][sub][kb][lane][8]
//      = W[sub*S1 + grp*S2 + (lane&15)][kb*32 + (lane>>4)*8 + j]
//  lstm:  S1=1024 (gate), S2=16 (ct)   -> BF[ct][gate][kb][..]
//  fc1:   S1=16,  S2=64                -> BF[ctq][nt ][kb][..]
//  fc2:   S1=16,  S2=0 (grp=0)         -> BF[0][nt][kb][..]

typedef f32x4 RedT[8][64];   // per-wave slab: 8 KB; 4 waves = 32 KB total

// ---------- LSTM cell unit (one (ct,mg) tile; block-wide, split-K by wave) ----------
__device__ __forceinline__ void lstm_unit(
    const u16* __restrict__ AFa, int KBa,
    const u16* __restrict__ BFa,
    const u16* __restrict__ AFh,
    const u16* __restrict__ BFh,
    const float* __restrict__ bsum,
    float* __restrict__ c,
    u16* __restrict__ h_out,
    int ct, int mg, int tid, RedT* red)
{
    const int w    = tid >> 6;
    const int lane = tid & 63;
    const int l15  = lane & 15;
    const int quad = lane >> 4;

    f32x4 acc[4][4];
    #pragma unroll
    for (int t = 0; t < 4; ++t)
        #pragma unroll
        for (int g = 0; g < 4; ++g) acc[t][g] = (f32x4){0, 0, 0, 0};

    // x-side: wave w takes kb quarter
    {
        const int q = KBa >> 2;
        #pragma unroll 2
        for (int kb = w * q; kb < w * q + q; ++kb) {
            f16x8 a[4], b[4];
            #pragma unroll
            for (int t = 0; t < 4; ++t)
                a[t] = ldfrag(AFa + (((size_t)(mg * 4 + t) * KBa + kb) * 64 + lane) * 8);
            #pragma unroll
            for (int g = 0; g < 4; ++g)
                b[g] = ldfrag(BFa + (((size_t)(ct * 4 + g) * KBa + kb) * 64 + lane) * 8);
            #pragma unroll
            for (int t = 0; t < 4; ++t)
                #pragma unroll
                for (int g = 0; g < 4; ++g)
                    acc[t][g] = __builtin_amdgcn_mfma_f32_16x16x32_f16(a[t], b[g], acc[t][g], 0, 0, 0);
        }
    }
    // h-side: KB=32, quarter = 8
    {
        #pragma unroll 2
        for (int kb = w * 8; kb < w * 8 + 8; ++kb) {
            f16x8 a[4], b[4];
            #pragma unroll
            for (int t = 0; t < 4; ++t)
                a[t] = ldfrag(AFh + (((size_t)(mg * 4 + t) * 32 + kb) * 64 + lane) * 8);
            #pragma unroll
            for (int g = 0; g < 4; ++g)
                b[g] = ldfrag(BFh + (((size_t)(ct * 4 + g) * 32 + kb) * 64 + lane) * 8);
            #pragma unroll
            for (int t = 0; t < 4; ++t)
                #pragma unroll
                for (int g = 0; g < 4; ++g)
                    acc[t][g] = __builtin_amdgcn_mfma_f32_16x16x32_f16(a[t], b[g], acc[t][g], 0, 0, 0);
        }
    }

    // cross-wave K-reduction via LDS, two passes (32 KB instead of 64 KB)
    f32x4 z[4];
    // pass A: mtile-subs 0,1 (owners: waves 0,1)
    #pragma unroll
    for (int t = 0; t < 2; ++t)
        #pragma unroll
        for (int g = 0; g < 4; ++g)
            red[w][t * 4 + g][lane] = acc[t][g];
    __syncthreads();
    if (w < 2)
        #pragma unroll
        for (int g = 0; g < 4; ++g)
            z[g] = red[0][w * 4 + g][lane] + red[1][w * 4 + g][lane] +
                   red[2][w * 4 + g][lane] + red[3][w * 4 + g][lane];
    __syncthreads();
    // pass B: mtile-subs 2,3 (owners: waves 2,3)
    #pragma unroll
    for (int t = 0; t < 2; ++t)
        #pragma unroll
        for (int g = 0; g < 4; ++g)
            red[w][t * 4 + g][lane] = acc[t + 2][g];
    __syncthreads();
    if (w >= 2)
        #pragma unroll
        for (int g = 0; g < 4; ++g)
            z[g] = red[0][(w - 2) * 4 + g][lane] + red[1][(w - 2) * 4 + g][lane] +
                   red[2][(w - 2) * 4 + g][lane] + red[3][(w - 2) * 4 + g][lane];
    __syncthreads();   // red reusable by next unit

    const int col   = ct * 16 + l15;
    const int mtile = mg * 4 + w;
    float bv[4];
    #pragma unroll
    for (int g = 0; g < 4; ++g) bv[g] = bsum[g * 1024 + col];
    const int hkb = col >> 5, hquad = (col >> 3) & 3, hj = col & 7;
    #pragma unroll
    for (int r = 0; r < 4; ++r) {
        const int rl  = quad * 4 + r;
        const int row = mtile * 16 + rl;
        const size_t gi = (size_t)row * 1024 + col;
        const float zi = z[0][r] + bv[0];
        const float zf = z[1][r] + bv[1];
        const float zg = z[2][r] + bv[2];
        const float zo = z[3][r] + bv[3];
        const float cv = c[gi];
        const float cn = sigmoidf_(zf) * cv + sigmoidf_(zi) * tanhf(zg);
        c[gi] = cn;
        h_out[(((size_t)mtile * 32 + hkb) * 64 + hquad * 16 + rl) * 8 + hj] =
            f2h(sigmoidf_(zo) * tanhf(cn));
    }
}

// ---------- fc1 unit: U = tanh(h1 @ fc_w1^T + b1) ----------
__device__ __forceinline__ void fc1_unit(
    const u16* __restrict__ AFx, const u16* __restrict__ BFw,
    const float* __restrict__ bias, u16* __restrict__ U,
    int ctq, int mg, int tid, RedT* red)
{
    const int w    = tid >> 6;
    const int lane = tid & 63;
    const int l15  = lane & 15;
    const int quad = lane >> 4;

    f32x4 acc[4][4];
    #pragma unroll
    for (int t = 0; t < 4; ++t)
        #pragma unroll
        for (int g = 0; g < 4; ++g) acc[t][g] = (f32x4){0, 0, 0, 0};

    #pragma unroll 2
    for (int kb = w * 8; kb < w * 8 + 8; ++kb) {
        f16x8 a[4], b[4];
        #pragma unroll
        for (int t = 0; t < 4; ++t)
            a[t] = ldfrag(AFx + (((size_t)(mg * 4 + t) * 32 + kb) * 64 + lane) * 8);
        #pragma unroll
        for (int g = 0; g < 4; ++g)
            b[g] = ldfrag(BFw + (((size_t)(ctq * 4 + g) * 32 + kb) * 64 + lane) * 8);
        #pragma unroll
        for (int t = 0; t < 4; ++t)
            #pragma unroll
            for (int g = 0; g < 4; ++g)
                acc[t][g] = __builtin_amdgcn_mfma_f32_16x16x32_f16(a[t], b[g], acc[t][g], 0, 0, 0);
    }

    f32x4 z[4];
    #pragma unroll
    for (int t = 0; t < 2; ++t)
        #pragma unroll
        for (int g = 0; g < 4; ++g)
            red[w][t * 4 + g][lane] = acc[t][g];
    __syncthreads();
    if (w < 2)
        #pragma unroll
        for (int g = 0; g < 4; ++g)
            z[g] = red[0][w * 4 + g][lane] + red[1][w * 4 + g][lane] +
                   red[2][w * 4 + g][lane] + red[3][w * 4 + g][lane];
    __syncthreads();
    #pragma unroll
    for (int t = 0; t < 2; ++t)
        #pragma unroll
        for (int g = 0; g < 4; ++g)
            red[w][t * 4 + g][lane] = acc[t + 2][g];
    __syncthreads();
    if (w >= 2)
        #pragma unroll
        for (int g = 0; g < 4; ++g)
            z[g] = red[0][(w - 2) * 4 + g][lane] + red[1][(w - 2) * 4 + g][lane] +
                   red[2][(w - 2) * 4 + g][lane] + red[3][(w - 2) * 4 + g][lane];
    __syncthreads();

    const int mtile = mg * 4 + w;
    #pragma unroll
    for (int g = 0; g < 4; ++g) {
        const int col = ctq * 64 + g * 16 + l15;
        const float bv = bias[col];
        const int ukb = col >> 5, uquad = (col >> 3) & 3, uj = col & 7;
        #pragma unroll
        for (int r = 0; r < 4; ++r) {
            const int rl = quad * 4 + r;
            U[(((size_t)mtile * 32 + ukb) * 64 + uquad * 16 + rl) * 8 + uj] =
                f2h(tanhf(z[g][r] + bv));
        }
    }
}

// ---------- fc2 unit: est = U @ fc_w2^T + b2 + est_in ----------
__device__ __forceinline__ void fc2_unit(
    const u16* __restrict__ AFu, const u16* __restrict__ BFw2,
    const float* __restrict__ b2,
    const float* __restrict__ est_in, float* __restrict__ est_out,
    float* __restrict__ out_t, u16* __restrict__ xdec_t,
    int mtile, int tid)
{
    const int w    = tid >> 6;
    const int lane = tid & 63;
    const int l15  = lane & 15;
    const int quad = lane >> 4;

    f32x4 accp[4] = {{0,0,0,0},{0,0,0,0},{0,0,0,0},{0,0,0,0}};
    const u16* ap = AFu + ((size_t)(mtile * 32) * 64 + lane) * 8;
    const u16* bp = BFw2 + ((size_t)(w * 32) * 64 + lane) * 8;
    #pragma unroll 4
    for (int kb = 0; kb < 32; ++kb)
        accp[kb & 3] = __builtin_amdgcn_mfma_f32_16x16x32_f16(
            ldfrag(ap + kb * 512), ldfrag(bp + kb * 512), accp[kb & 3], 0, 0, 0);
    f32x4 acc = accp[0] + accp[1] + accp[2] + accp[3];

    const int col = w * 16 + l15;
    const float bv = b2[col];
    const int cx = 192 + col;
    const int xkb = cx >> 5, xquad = (cx >> 3) & 3, xj = cx & 7;
    #pragma unroll
    for (int r = 0; r < 4; ++r) {
        const int rl = quad * 4 + r;
        const int row = mtile * 16 + rl;
        const float v = acc[r] + bv + est_in[row * 64 + col];
        est_out[row * 64 + col] = v;
        out_t[row * 64 + col] = v;
        xdec_t[(((size_t)mtile * 8 + xkb) * 64 + xquad * 16 + rl) * 8 + xj] = f2h(v);
    }
}

// ---------- shared parameter block ----------
struct MegaP {
    const u16 *xyenc; u16 *xdec;
    const u16 *wih0, *whh0, *wih1, *whh1, *fcw1, *fcw2;
    const float *b0s, *b1s, *fcb1, *fcb2;
    float *c0, *c1, *est0, *est1, *out;
    u16 *h0a, *h0b, *h1a, *h1b, *U;
};

// ---------- persistent cooperative mega-kernel ----------
__global__ __launch_bounds__(256, 1) void mega_k(MegaP p) {
    cg::grid_group grid = cg::this_grid();
    __shared__ f32x4 red[4][8][64];   // 32 KB
    const int b   = blockIdx.x;
    const int tid = threadIdx.x;
    const int ct  = b & 63;
    const int mg  = b >> 6;

    u16* h0buf[2] = { p.h0a, p.h0b };
    u16* h1buf[2] = { p.h1a, p.h1b };
    float* estb[2] = { p.est0, p.est1 };

    // encode: 65 phases, L0(ph) || L1(ph-1)
    for (int ph = 0; ph <= 64; ++ph) {
        if (ph < 64)
            lstm_unit(p.xyenc + (size_t)ph * 65536, 8, p.wih0,
                      h0buf[ph & 1], p.whh0, p.b0s, p.c0, h0buf[(ph + 1) & 1],
                      ct, mg, tid, red);
        if (ph >= 1) {
            const int t = ph - 1;
            lstm_unit(h0buf[(t + 1) & 1], 32, p.wih1,
                      h1buf[t & 1], p.whh1, p.b1s, p.c1, h1buf[(t + 1) & 1],
                      ct, mg, tid, red);
        }
        grid.sync();
    }

    // decode: 48 steps x 4 phases
    int cur = 0;
    for (int t = 0; t < 48; ++t) {
        if (b < 64)
            fc1_unit(h1buf[cur], p.fcw1, p.fcb1, p.U, b & 15, b >> 4, tid, red);
        grid.sync();
        if (b < 16)
            fc2_unit(p.U, p.fcw2, p.fcb2, estb[t & 1], estb[(t + 1) & 1],
                     p.out + (size_t)t * 16384, p.xdec + (size_t)t * 65536, b, tid);
        grid.sync();
        lstm_unit(p.xdec + (size_t)t * 65536, 8, p.wih0,
                  h0buf[cur], p.whh0, p.b0s, p.c0, h0buf[cur ^ 1],
                  ct, mg, tid, red);
        grid.sync();
        lstm_unit(h0buf[cur ^ 1], 32, p.wih1,
                  h1buf[cur], p.whh1, p.b1s, p.c1, h1buf[cur ^ 1],
                  ct, mg, tid, red);
        grid.sync();
        cur ^= 1;
    }
}

// ---------- fallback kernels (used only if cooperative launch is rejected) ----------
// encode phase: 512 blocks; 0..255 -> L0(ph), 256..511 -> L1(ph-1)
__global__ __launch_bounds__(256, 2) void enc_phase_k(MegaP p, int ph) {
    __shared__ f32x4 red[4][8][64];
    const int b   = blockIdx.x;
    const int tid = threadIdx.x;
    u16* h0buf[2] = { p.h0a, p.h0b };
    u16* h1buf[2] = { p.h1a, p.h1b };
    if (b < 256) {
        if (ph < 64)
            lstm_unit(p.xyenc + (size_t)ph * 65536, 8, p.wih0,
                      h0buf[ph & 1], p.whh0, p.b0s, p.c0, h0buf[(ph + 1) & 1],
                      b & 63, b >> 6, tid, red);
    } else {
        if (ph >= 1) {
            const int t = ph - 1, bb = b - 256;
            lstm_unit(h0buf[(t + 1) & 1], 32, p.wih1,
                      h1buf[t & 1], p.whh1, p.b1s, p.c1, h1buf[(t + 1) & 1],
                      bb & 63, bb >> 6, tid, red);
        }
    }
}
__global__ __launch_bounds__(256, 2) void fc1_fb_k(MegaP p, int cur) {
    __shared__ f32x4 red[4][8][64];
    u16* h1buf[2] = { p.h1a, p.h1b };
    fc1_unit(h1buf[cur], p.fcw1, p.fcb1, p.U,
             blockIdx.x & 15, blockIdx.x >> 4, threadIdx.x, red);
}
__global__ __launch_bounds__(256, 2) void fc2_fb_k(MegaP p, int t) {
    float* estb[2] = { p.est0, p.est1 };
    fc2_unit(p.U, p.fcw2, p.fcb2, estb[t & 1], estb[(t + 1) & 1],
             p.out + (size_t)t * 16384, p.xdec + (size_t)t * 65536,
             blockIdx.x, threadIdx.x);
}
__global__ __launch_bounds__(256, 2) void l0_fb_k(MegaP p, int t, int cur) {
    __shared__ f32x4 red[4][8][64];
    u16* h0buf[2] = { p.h0a, p.h0b };
    lstm_unit(p.xdec + (size_t)t * 65536, 8, p.wih0,
              h0buf[cur], p.whh0, p.b0s, p.c0, h0buf[cur ^ 1],
              blockIdx.x & 63, blockIdx.x >> 6, threadIdx.x, red);
}
__global__ __launch_bounds__(256, 2) void l1_fb_k(MegaP p, int cur) {
    __shared__ f32x4 red[4][8][64];
    u16* h0buf[2] = { p.h0a, p.h0b };
    u16* h1buf[2] = { p.h1a, p.h1b };
    lstm_unit(h0buf[cur ^ 1], 32, p.wih1,
              h1buf[cur], p.whh1, p.b1s, p.c1, h1buf[cur ^ 1],
              blockIdx.x & 63, blockIdx.x >> 6, threadIdx.x, red);
}

// ---------- setup kernels ----------
__global__ void cvt_bfrag_k(const float* __restrict__ src, u16* __restrict__ dst,
                            int K, int kbshift, int S1, int S2, int total) {
    int i = blockIdx.x * 256 + threadIdx.x;
    if (i >= total) return;
    const int lane = i & 63;
    const int kb   = (i >> 6) & ((1 << kbshift) - 1);
    const int rest = i >> (6 + kbshift);
    const int sub  = rest & 3;
    const int grp  = rest >> 2;
    const int row  = sub * S1 + grp * S2 + (lane & 15);
    const int colK = kb * 32 + (lane >> 4) * 8;
    const float* s = src + (size_t)row * K + colK;
    u16* d = dst + (size_t)i * 8;
    #pragma unroll
    for (int j = 0; j < 8; ++j) d[j] = f2h(s[j]);
}
__global__ void bias_k(const float* __restrict__ a, const float* __restrict__ b,
                       float* __restrict__ d, int n) {
    int i = blockIdx.x * 256 + threadIdx.x;
    if (i < n) d[i] = a[i] + b[i];
}
__global__ void init_k(u16* h0, u16* h1, float* c0, float* c1) {  // n = 256*1024
    int i = blockIdx.x * 256 + threadIdx.x;
    h0[i] = 0; h1[i] = 0; c0[i] = 0.0f; c1[i] = 0.0f;
}
__global__ void estinit_k(const float* __restrict__ pre_y, float* __restrict__ est_prev) {
    int i = blockIdx.x * 256 + threadIdx.x;   // n = 256*64
    est_prev[i] = pre_y[63 * 16384 + i];      // pre_y[-1]
}
__global__ void pack_enc_k(const float* __restrict__ pre_x, const float* __restrict__ pre_y,
                           u16* __restrict__ xy) {   // threads = 64*16*8*64
    int i = blockIdx.x * 256 + threadIdx.x;
    const int lane  = i & 63;
    const int kb    = (i >> 6) & 7;
    const int mtile = (i >> 9) & 15;
    const int t     = i >> 13;
    const int row   = mtile * 16 + (lane & 15);
    const int cb    = kb * 32 + (lane >> 4) * 8;
    u16* d = xy + (size_t)i * 8;
    #pragma unroll
    for (int j = 0; j < 8; ++j) {
        const int col = cb + j;
        const float v = (col < 192) ? pre_x[((size_t)t * 256 + row) * 192 + col]
                                    : pre_y[((size_t)t * 256 + row) * 64 + (col - 192)];
        d[j] = f2h(v);
    }
}
__global__ void pack_dec_k(const float* __restrict__ fx, u16* __restrict__ xd,
                           int total_threads) {      // threads = 48*16*6*64
    int i = blockIdx.x * 256 + threadIdx.x;
    if (i >= total_threads) return;
    const int lane  = i & 63;
    int rest = i >> 6;
    const int kb    = rest % 6;  rest /= 6;
    const int mtile = rest & 15;
    const int t     = rest >> 4;
    const int row   = mtile * 16 + (lane & 15);
    const int cb    = kb * 32 + (lane >> 4) * 8;
    u16* d = xd + ((((size_t)t * 16 + mtile) * 8 + kb) * 64 + lane) * 8;
    #pragma unroll
    for (int j = 0; j < 8; ++j)
        d[j] = f2h(fx[((size_t)t * 256 + row) * 192 + cb + j]);
}

extern "C" void kernel_launch(void* const* d_in, const int* in_sizes, int n_in,
                              void* d_out, int out_size, void* d_ws, size_t ws_size,
                              hipStream_t stream) {
    const float* pre_x  = (const float*)d_in[0];
    const float* pre_y  = (const float*)d_in[1];
    const float* fx     = (const float*)d_in[2];
    const float* w_ih_0 = (const float*)d_in[3];
    const float* w_hh_0 = (const float*)d_in[4];
    const float* b_ih_0 = (const float*)d_in[5];
    const float* b_hh_0 = (const float*)d_in[6];
    const float* w_ih_1 = (const float*)d_in[7];
    const float* w_hh_1 = (const float*)d_in[8];
    const float* b_ih_1 = (const float*)d_in[9];
    const float* b_hh_1 = (const float*)d_in[10];
    const float* fc_w1  = (const float*)d_in[11];
    const float* fc_b1  = (const float*)d_in[12];
    const float* fc_w2  = (const float*)d_in[13];
    const float* fc_b2  = (const float*)d_in[14];

    size_t off = 0;
    char* wsb = (char*)d_ws;
    auto alloc = [&](size_t bytes) -> void* {
        void* p = wsb + off;
        off += (bytes + 255) & ~(size_t)255;
        return p;
    };
    u16* wih0 = (u16*)alloc((size_t)4096 * 256 * 2);
    u16* whh0 = (u16*)alloc((size_t)4096 * 1024 * 2);
    u16* wih1 = (u16*)alloc((size_t)4096 * 1024 * 2);
    u16* whh1 = (u16*)alloc((size_t)4096 * 1024 * 2);
    u16* fcw1 = (u16*)alloc((size_t)1024 * 1024 * 2);
    u16* fcw2 = (u16*)alloc((size_t)64 * 1024 * 2);
    float* b0s = (float*)alloc(4096 * 4);
    float* b1s = (float*)alloc(4096 * 4);
    u16* xyenc = (u16*)alloc((size_t)64 * 256 * 256 * 2);
    u16* xdec  = (u16*)alloc((size_t)48 * 256 * 256 * 2);
    u16* h0a = (u16*)alloc((size_t)256 * 1024 * 2);
    u16* h0b = (u16*)alloc((size_t)256 * 1024 * 2);
    u16* h1a = (u16*)alloc((size_t)256 * 1024 * 2);
    u16* h1b = (u16*)alloc((size_t)256 * 1024 * 2);
    float* c0 = (float*)alloc((size_t)256 * 1024 * 4);
    float* c1 = (float*)alloc((size_t)256 * 1024 * 4);
    u16* ufc  = (u16*)alloc((size_t)256 * 1024 * 2);
    float* est0 = (float*)alloc((size_t)256 * 64 * 4);
    float* est1 = (float*)alloc((size_t)256 * 64 * 4);

    // --- setup ---
    cvt_bfrag_k<<<512, 256, 0, stream>>>(w_ih_0, wih0, 256, 3, 1024, 16, 64 * 4 * 8 * 64);
    cvt_bfrag_k<<<2048, 256, 0, stream>>>(w_hh_0, whh0, 1024, 5, 1024, 16, 64 * 4 * 32 * 64);
    cvt_bfrag_k<<<2048, 256, 0, stream>>>(w_ih_1, wih1, 1024, 5, 1024, 16, 64 * 4 * 32 * 64);
    cvt_bfrag_k<<<2048, 256, 0, stream>>>(w_hh_1, whh1, 1024, 5, 1024, 16, 64 * 4 * 32 * 64);
    cvt_bfrag_k<<<512, 256, 0, stream>>>(fc_w1, fcw1, 1024, 5, 16, 64, 16 * 4 * 32 * 64);
    cvt_bfrag_k<<<32, 256, 0, stream>>>(fc_w2, fcw2, 1024, 5, 16, 0, 1 * 4 * 32 * 64);
    bias_k<<<16, 256, 0, stream>>>(b_ih_0, b_hh_0, b0s, 4096);
    bias_k<<<16, 256, 0, stream>>>(b_ih_1, b_hh_1, b1s, 4096);
    init_k<<<1024, 256, 0, stream>>>(h0a, h1a, c0, c1);
    estinit_k<<<64, 256, 0, stream>>>(pre_y, est0);
    pack_enc_k<<<2048, 256, 0, stream>>>(pre_x, pre_y, xyenc);
    pack_dec_k<<<1152, 256, 0, stream>>>(fx, xdec, 48 * 16 * 6 * 64);

    MegaP prm;
    prm.xyenc = xyenc;  prm.xdec = xdec;
    prm.wih0 = wih0;  prm.whh0 = whh0;  prm.wih1 = wih1;  prm.whh1 = whh1;
    prm.fcw1 = fcw1;  prm.fcw2 = fcw2;
    prm.b0s = b0s;  prm.b1s = b1s;  prm.fcb1 = fc_b1;  prm.fcb2 = fc_b2;
    prm.c0 = c0;  prm.c1 = c1;  prm.est0 = est0;  prm.est1 = est1;
    prm.out = (float*)d_out;
    prm.h0a = h0a;  prm.h0b = h0b;  prm.h1a = h1a;  prm.h1b = h1b;  prm.U = ufc;

    // --- primary: one persistent cooperative kernel ---
    void* kargs[] = { (void*)&prm };
    hipError_t ce = hipLaunchCooperativeKernel((const void*)mega_k, dim3(256), dim3(256),
                                               kargs, 0, stream);
    if (ce != hipSuccess) {
        // --- fallback: multi-launch (encode pipelined across layers) ---
        for (int ph = 0; ph <= 64; ++ph)
            enc_phase_k<<<512, 256, 0, stream>>>(prm, ph);
        int cur = 0;
        for (int t = 0; t < 48; ++t) {
            fc1_fb_k<<<64, 256, 0, stream>>>(prm, cur);
            fc2_fb_k<<<16, 256, 0, stream>>>(prm, t);
            l0_fb_k<<<256, 256, 0, stream>>>(prm, t, cur);
            l1_fb_k<<<256, 256, 0, stream>>>(prm, cur);
            cur ^= 1;
        }
    }
}

// Round 7
// 4327.570 us; speedup vs baseline: 2.5684x; 2.5684x over previous
//
#include <hip/hip_runtime.h>
#include <stdint.h>

typedef unsigned short u16;
typedef unsigned long long u64;
typedef __attribute__((ext_vector_type(8))) _Float16 f16x8;
typedef __attribute__((ext_vector_type(4))) float f32x4;

#define AGT __HIP_MEMORY_SCOPE_AGENT

// ---------- helpers ----------
__device__ inline f16x8 ldfrag(const u16* p) { return *(const f16x8*)p; }   // cached (weights)
__device__ inline u64 ldq_dev(const void* p) {                               // LLC-coherent load
    return __hip_atomic_load((const u64*)p, __ATOMIC_RELAXED, AGT);
}
__device__ inline void stq_dev(void* p, u64 v) {                             // LLC-coherent store
    __hip_atomic_store((u64*)p, v, __ATOMIC_RELAXED, AGT);
}
__device__ inline f16x8 ldfrag_dev(const u16* p) {                           // 16B frag via 2x8B
    union { u64 q[2]; f16x8 v; } u;
    u.q[0] = ldq_dev(p);
    u.q[1] = ldq_dev(p + 4);
    return u.v;
}
__device__ inline u16 f2h(float x) {
    _Float16 h = (_Float16)x;
    union { _Float16 h; u16 u; } v; v.h = h;
    return v.u;
}
__device__ inline float sigmoidf_(float x) { return 1.0f / (1.0f + expf(-x)); }

// grid barrier WITHOUT L2 invalidation: per-phase counter, device-scope atomics.
// __syncthreads() before arrival drains each wave's vmcnt (sc1 stores are then at LLC).
__device__ inline void gbar(unsigned* bars, int ph) {
    __syncthreads();
    if (threadIdx.x == 0) {
        __hip_atomic_fetch_add(&bars[ph], 1u, __ATOMIC_RELAXED, AGT);
        while (__hip_atomic_load(&bars[ph], __ATOMIC_RELAXED, AGT) < 256u)
            __builtin_amdgcn_s_sleep(2);
    }
    __syncthreads();
}

// Layouts (fp16 as u16):
//  A-frag (X: 256 x K):  AF[mtile][kb][lane][8] = X[mtile*16+(lane&15)][kb*32+(lane>>4)*8+j]
//  B-frag (W: N x K):    BF[grp][sub][kb][lane][8], row = sub*S1 + grp*S2 + (lane&15)
//  lstm: S1=1024,S2=16 -> BF[ct][gate][..]; fc1: S1=16,S2=64; fc2: S1=16,grp=0
// Cross-block activations (h0,h1,U,xdec-est) are accessed ONLY via ldfrag_dev/stq_dev.

typedef f32x4 RedT[8][64];   // 4 waves x 8KB = 32 KB

// ---------- LSTM cell unit ----------
__device__ __forceinline__ void lstm_unit(
    const u16* __restrict__ AFa, int KBa,
    const u16* __restrict__ BFa,
    const u16* __restrict__ AFh,
    const u16* __restrict__ BFh,
    const float* __restrict__ bsum,
    float* __restrict__ c,
    u16* __restrict__ h_out,
    int ct, int mg, int tid, RedT* red, u16* stage)
{
    const int w    = tid >> 6;
    const int lane = tid & 63;
    const int l15  = lane & 15;
    const int quad = lane >> 4;

    f32x4 acc[4][4];
    #pragma unroll
    for (int t = 0; t < 4; ++t)
        #pragma unroll
        for (int g = 0; g < 4; ++g) acc[t][g] = (f32x4){0, 0, 0, 0};

    // x-side: wave w takes kb quarter (activations -> coherent loads)
    {
        const int q = KBa >> 2;
        #pragma unroll 2
        for (int kb = w * q; kb < w * q + q; ++kb) {
            f16x8 a[4], b[4];
            #pragma unroll
            for (int t = 0; t < 4; ++t)
                a[t] = ldfrag_dev(AFa + (((size_t)(mg * 4 + t) * KBa + kb) * 64 + lane) * 8);
            #pragma unroll
            for (int g = 0; g < 4; ++g)
                b[g] = ldfrag(BFa + (((size_t)(ct * 4 + g) * KBa + kb) * 64 + lane) * 8);
            #pragma unroll
            for (int t = 0; t < 4; ++t)
                #pragma unroll
                for (int g = 0; g < 4; ++g)
                    acc[t][g] = __builtin_amdgcn_mfma_f32_16x16x32_f16(a[t], b[g], acc[t][g], 0, 0, 0);
        }
    }
    // h-side: KB=32, quarter=8
    {
        #pragma unroll 2
        for (int kb = w * 8; kb < w * 8 + 8; ++kb) {
            f16x8 a[4], b[4];
            #pragma unroll
            for (int t = 0; t < 4; ++t)
                a[t] = ldfrag_dev(AFh + (((size_t)(mg * 4 + t) * 32 + kb) * 64 + lane) * 8);
            #pragma unroll
            for (int g = 0; g < 4; ++g)
                b[g] = ldfrag(BFh + (((size_t)(ct * 4 + g) * 32 + kb) * 64 + lane) * 8);
            #pragma unroll
            for (int t = 0; t < 4; ++t)
                #pragma unroll
                for (int g = 0; g < 4; ++g)
                    acc[t][g] = __builtin_amdgcn_mfma_f32_16x16x32_f16(a[t], b[g], acc[t][g], 0, 0, 0);
        }
    }

    // cross-wave K-reduction via LDS, two passes (32 KB)
    f32x4 z[4];
    #pragma unroll
    for (int t = 0; t < 2; ++t)
        #pragma unroll
        for (int g = 0; g < 4; ++g)
            red[w][t * 4 + g][lane] = acc[t][g];
    __syncthreads();
    if (w < 2)
        #pragma unroll
        for (int g = 0; g < 4; ++g)
            z[g] = red[0][w * 4 + g][lane] + red[1][w * 4 + g][lane] +
                   red[2][w * 4 + g][lane] + red[3][w * 4 + g][lane];
    __syncthreads();
    #pragma unroll
    for (int t = 0; t < 2; ++t)
        #pragma unroll
        for (int g = 0; g < 4; ++g)
            red[w][t * 4 + g][lane] = acc[t + 2][g];
    __syncthreads();
    if (w >= 2)
        #pragma unroll
        for (int g = 0; g < 4; ++g)
            z[g] = red[0][(w - 2) * 4 + g][lane] + red[1][(w - 2) * 4 + g][lane] +
                   red[2][(w - 2) * 4 + g][lane] + red[3][(w - 2) * 4 + g][lane];

    const int col = ct * 16 + l15;
    float bv[4];
    #pragma unroll
    for (int g = 0; g < 4; ++g) bv[g] = bsum[g * 1024 + col];
    const int mtile = mg * 4 + w;
    #pragma unroll
    for (int r = 0; r < 4; ++r) {
        const int rl  = quad * 4 + r;
        const int row = mtile * 16 + rl;
        const size_t gi = (size_t)row * 1024 + col;
        const float zi = z[0][r] + bv[0];
        const float zf = z[1][r] + bv[1];
        const float zg = z[2][r] + bv[2];
        const float zo = z[3][r] + bv[3];
        const float cv = c[gi];                       // c is block-private: cached
        const float cn = sigmoidf_(zf) * cv + sigmoidf_(zi) * tanhf(zg);
        c[gi] = cn;
        stage[(w * 16 + rl) * 16 + l15] = f2h(sigmoidf_(zo) * tanhf(cn));
    }
    __syncthreads();
    // repack 64x16 tile -> A-frag layout, 8B coherent stores (256 x u64)
    {
        const int half  = tid & 1;
        const int chunk = tid >> 1;          // 0..127
        const int qh    = chunk & 1;
        const int rb    = chunk >> 1;        // 0..63
        const int mt    = mg * 4 + (rb >> 4), rl = rb & 15;
        const int hkb   = ct >> 1, hq = (ct & 1) * 2 + qh;
        u64 v = *(const u64*)&stage[rb * 16 + qh * 8 + half * 4];
        stq_dev(h_out + (((size_t)mt * 32 + hkb) * 64 + hq * 16 + rl) * 8 + half * 4, v);
    }
}

// ---------- fc1 unit: U = tanh(h1 @ fc_w1^T + b1) ----------
__device__ __forceinline__ void fc1_unit(
    const u16* __restrict__ AFx, const u16* __restrict__ BFw,
    const float* __restrict__ bias, u16* __restrict__ U,
    int ctq, int mg, int tid, RedT* red, u16* stage)
{
    const int w    = tid >> 6;
    const int lane = tid & 63;
    const int l15  = lane & 15;
    const int quad = lane >> 4;

    f32x4 acc[4][4];
    #pragma unroll
    for (int t = 0; t < 4; ++t)
        #pragma unroll
        for (int g = 0; g < 4; ++g) acc[t][g] = (f32x4){0, 0, 0, 0};

    #pragma unroll 2
    for (int kb = w * 8; kb < w * 8 + 8; ++kb) {
        f16x8 a[4], b[4];
        #pragma unroll
        for (int t = 0; t < 4; ++t)
            a[t] = ldfrag_dev(AFx + (((size_t)(mg * 4 + t) * 32 + kb) * 64 + lane) * 8);
        #pragma unroll
        for (int g = 0; g < 4; ++g)
            b[g] = ldfrag(BFw + (((size_t)(ctq * 4 + g) * 32 + kb) * 64 + lane) * 8);
        #pragma unroll
        for (int t = 0; t < 4; ++t)
            #pragma unroll
            for (int g = 0; g < 4; ++g)
                acc[t][g] = __builtin_amdgcn_mfma_f32_16x16x32_f16(a[t], b[g], acc[t][g], 0, 0, 0);
    }

    f32x4 z[4];
    #pragma unroll
    for (int t = 0; t < 2; ++t)
        #pragma unroll
        for (int g = 0; g < 4; ++g)
            red[w][t * 4 + g][lane] = acc[t][g];
    __syncthreads();
    if (w < 2)
        #pragma unroll
        for (int g = 0; g < 4; ++g)
            z[g] = red[0][w * 4 + g][lane] + red[1][w * 4 + g][lane] +
                   red[2][w * 4 + g][lane] + red[3][w * 4 + g][lane];
    __syncthreads();
    #pragma unroll
    for (int t = 0; t < 2; ++t)
        #pragma unroll
        for (int g = 0; g < 4; ++g)
            red[w][t * 4 + g][lane] = acc[t + 2][g];
    __syncthreads();
    if (w >= 2)
        #pragma unroll
        for (int g = 0; g < 4; ++g)
            z[g] = red[0][(w - 2) * 4 + g][lane] + red[1][(w - 2) * 4 + g][lane] +
                   red[2][(w - 2) * 4 + g][lane] + red[3][(w - 2) * 4 + g][lane];

    #pragma unroll
    for (int g = 0; g < 4; ++g) {
        const float bv = bias[ctq * 64 + g * 16 + l15];
        #pragma unroll
        for (int r = 0; r < 4; ++r)
            stage[(w * 16 + quad * 4 + r) * 64 + g * 16 + l15] = f2h(tanhf(z[g][r] + bv));
    }
    __syncthreads();
    // repack 64x64 tile -> A-frag layout (1024 x u64, 4 per thread)
    #pragma unroll
    for (int s = 0; s < 4; ++s) {
        const int i    = s * 256 + tid;
        const int half = i & 1;
        const int cg   = (i >> 1) & 7;
        const int rb   = i >> 4;            // 0..63
        const int col0 = ctq * 64 + cg * 8;
        const int ukb  = col0 >> 5, uq = (col0 >> 3) & 3;
        const int mt   = mg * 4 + (rb >> 4), rl = rb & 15;
        u64 v = *(const u64*)&stage[rb * 64 + cg * 8 + half * 4];
        stq_dev(U + (((size_t)mt * 32 + ukb) * 64 + uq * 16 + rl) * 8 + half * 4, v);
    }
}

// ---------- fc2 unit: est = U @ fc_w2^T + b2 + est_in ----------
__device__ __forceinline__ void fc2_unit(
    const u16* __restrict__ AFu, const u16* __restrict__ BFw2,
    const float* __restrict__ b2,
    const float* __restrict__ est_in, float* __restrict__ est_out,
    float* __restrict__ out_t, u16* __restrict__ xdec_t,
    int mtile, int tid, u16* stage)
{
    const int w    = tid >> 6;
    const int lane = tid & 63;
    const int l15  = lane & 15;
    const int quad = lane >> 4;

    f32x4 accp[4] = {{0,0,0,0},{0,0,0,0},{0,0,0,0},{0,0,0,0}};
    const u16* ap = AFu + ((size_t)(mtile * 32) * 64 + lane) * 8;
    const u16* bp = BFw2 + ((size_t)(w * 32) * 64 + lane) * 8;
    #pragma unroll 4
    for (int kb = 0; kb < 32; ++kb)
        accp[kb & 3] = __builtin_amdgcn_mfma_f32_16x16x32_f16(
            ldfrag_dev(ap + kb * 512), ldfrag(bp + kb * 512), accp[kb & 3], 0, 0, 0);
    f32x4 acc = accp[0] + accp[1] + accp[2] + accp[3];

    const int col = w * 16 + l15;
    const float bv = b2[col];
    #pragma unroll
    for (int r = 0; r < 4; ++r) {
        const int rl = quad * 4 + r;
        const int row = mtile * 16 + rl;
        const float v = acc[r] + bv + est_in[row * 64 + col];   // est: block-private ping-pong
        est_out[row * 64 + col] = v;
        out_t[row * 64 + col] = v;
        stage[rl * 64 + col] = f2h(v);
    }
    __syncthreads();
    // repack 16x64 est tile -> xdec A-frag est cols (256 x u64)
    {
        const int half = tid & 1;
        const int cg   = (tid >> 1) & 7;
        const int rr   = tid >> 4;          // 0..15
        const int col0 = 192 + cg * 8;
        const int xkb  = col0 >> 5, xq = (col0 >> 3) & 3;
        u64 v = *(const u64*)&stage[rr * 64 + cg * 8 + half * 4];
        stq_dev(xdec_t + (((size_t)mtile * 8 + xkb) * 64 + xq * 16 + rr) * 8 + half * 4, v);
    }
}

// ---------- shared parameter block ----------
struct MegaP {
    const u16 *xyenc; u16 *xdec;
    const u16 *wih0, *whh0, *wih1, *whh1, *fcw1, *fcw2;
    const float *b0s, *b1s, *fcb1, *fcb2;
    float *c0, *c1, *est0, *est1, *out;
    u16 *h0a, *h0b, *h1a, *h1b, *U;
    unsigned *bars;
};

// ---------- persistent mega-kernel (custom barrier, no L2 invalidation) ----------
__global__ __launch_bounds__(256, 1) void mega_k(MegaP p) {
    __shared__ f32x4 red[4][8][64];   // 32 KB
    __shared__ u16 stage[4096];       // 8 KB
    const int b   = blockIdx.x;
    const int tid = threadIdx.x;
    const int ct  = b & 63;           // ct%8 == b%8 -> XCD-stable weight slices
    const int mg  = b >> 6;

    u16* h0buf[2] = { p.h0a, p.h0b };
    u16* h1buf[2] = { p.h1a, p.h1b };
    float* estb[2] = { p.est0, p.est1 };
    int ph = 0;

    // encode: 65 phases, L0(ph) || L1(ph-1)
    for (int s = 0; s <= 64; ++s) {
        if (s < 64)
            lstm_unit(p.xyenc + (size_t)s * 65536, 8, p.wih0,
                      h0buf[s & 1], p.whh0, p.b0s, p.c0, h0buf[(s + 1) & 1],
                      ct, mg, tid, red, stage);
        if (s >= 1) {
            const int t = s - 1;
            lstm_unit(h0buf[(t + 1) & 1], 32, p.wih1,
                      h1buf[t & 1], p.whh1, p.b1s, p.c1, h1buf[(t + 1) & 1],
                      ct, mg, tid, red, stage);
        }
        gbar(p.bars, ph++);
    }

    // decode: 48 steps x 4 phases
    int cur = 0;
    for (int t = 0; t < 48; ++t) {
        if (b < 64)
            fc1_unit(h1buf[cur], p.fcw1, p.fcb1, p.U, b & 15, b >> 4, tid, red, stage);
        gbar(p.bars, ph++);
        if (b < 16)
            fc2_unit(p.U, p.fcw2, p.fcb2, estb[t & 1], estb[(t + 1) & 1],
                     p.out + (size_t)t * 16384, p.xdec + (size_t)t * 65536, b, tid, stage);
        gbar(p.bars, ph++);
        lstm_unit(p.xdec + (size_t)t * 65536, 8, p.wih0,
                  h0buf[cur], p.whh0, p.b0s, p.c0, h0buf[cur ^ 1],
                  ct, mg, tid, red, stage);
        gbar(p.bars, ph++);
        lstm_unit(h0buf[cur ^ 1], 32, p.wih1,
                  h1buf[cur], p.whh1, p.b1s, p.c1, h1buf[cur ^ 1],
                  ct, mg, tid, red, stage);
        gbar(p.bars, ph++);
        cur ^= 1;
    }
}

// ---------- fallback kernels (multi-launch; kernel boundaries give coherence) ----------
__global__ __launch_bounds__(256, 2) void enc_phase_k(MegaP p, int ph) {
    __shared__ f32x4 red[4][8][64];
    __shared__ u16 stage[4096];
    const int b   = blockIdx.x;
    const int tid = threadIdx.x;
    u16* h0buf[2] = { p.h0a, p.h0b };
    u16* h1buf[2] = { p.h1a, p.h1b };
    if (b < 256) {
        if (ph < 64)
            lstm_unit(p.xyenc + (size_t)ph * 65536, 8, p.wih0,
                      h0buf[ph & 1], p.whh0, p.b0s, p.c0, h0buf[(ph + 1) & 1],
                      b & 63, b >> 6, tid, red, stage);
    } else {
        if (ph >= 1) {
            const int t = ph - 1, bb = b - 256;
            lstm_unit(h0buf[(t + 1) & 1], 32, p.wih1,
                      h1buf[t & 1], p.whh1, p.b1s, p.c1, h1buf[(t + 1) & 1],
                      bb & 63, bb >> 6, tid, red, stage);
        }
    }
}
__global__ __launch_bounds__(256, 2) void fc1_fb_k(MegaP p, int cur) {
    __shared__ f32x4 red[4][8][64];
    __shared__ u16 stage[4096];
    u16* h1buf[2] = { p.h1a, p.h1b };
    fc1_unit(h1buf[cur], p.fcw1, p.fcb1, p.U,
             blockIdx.x & 15, blockIdx.x >> 4, threadIdx.x, red, stage);
}
__global__ __launch_bounds__(256, 2) void fc2_fb_k(MegaP p, int t) {
    __shared__ u16 stage[4096];
    float* estb[2] = { p.est0, p.est1 };
    fc2_unit(p.U, p.fcw2, p.fcb2, estb[t & 1], estb[(t + 1) & 1],
             p.out + (size_t)t * 16384, p.xdec + (size_t)t * 65536,
             blockIdx.x, threadIdx.x, stage);
}
__global__ __launch_bounds__(256, 2) void l0_fb_k(MegaP p, int t, int cur) {
    __shared__ f32x4 red[4][8][64];
    __shared__ u16 stage[4096];
    u16* h0buf[2] = { p.h0a, p.h0b };
    lstm_unit(p.xdec + (size_t)t * 65536, 8, p.wih0,
              h0buf[cur], p.whh0, p.b0s, p.c0, h0buf[cur ^ 1],
              blockIdx.x & 63, blockIdx.x >> 6, threadIdx.x, red, stage);
}
__global__ __launch_bounds__(256, 2) void l1_fb_k(MegaP p, int cur) {
    __shared__ f32x4 red[4][8][64];
    __shared__ u16 stage[4096];
    u16* h0buf[2] = { p.h0a, p.h0b };
    u16* h1buf[2] = { p.h1a, p.h1b };
    lstm_unit(h0buf[cur ^ 1], 32, p.wih1,
              h1buf[cur], p.whh1, p.b1s, p.c1, h1buf[cur ^ 1],
              blockIdx.x & 63, blockIdx.x >> 6, threadIdx.x, red, stage);
}

// ---------- setup kernels ----------
__global__ void cvt_bfrag_k(const float* __restrict__ src, u16* __restrict__ dst,
                            int K, int kbshift, int S1, int S2, int total) {
    int i = blockIdx.x * 256 + threadIdx.x;
    if (i >= total) return;
    const int lane = i & 63;
    const int kb   = (i >> 6) & ((1 << kbshift) - 1);
    const int rest = i >> (6 + kbshift);
    const int sub  = rest & 3;
    const int grp  = rest >> 2;
    const int row  = sub * S1 + grp * S2 + (lane & 15);
    const int colK = kb * 32 + (lane >> 4) * 8;
    const float* s = src + (size_t)row * K + colK;
    u16* d = dst + (size_t)i * 8;
    #pragma unroll
    for (int j = 0; j < 8; ++j) d[j] = f2h(s[j]);
}
__global__ void bias_k(const float* __restrict__ a, const float* __restrict__ b,
                       float* __restrict__ d, int n) {
    int i = blockIdx.x * 256 + threadIdx.x;
    if (i < n) d[i] = a[i] + b[i];
}
__global__ void init_k(u16* h0, u16* h1, float* c0, float* c1) {  // n = 256*1024
    int i = blockIdx.x * 256 + threadIdx.x;
    h0[i] = 0; h1[i] = 0; c0[i] = 0.0f; c1[i] = 0.0f;
}
__global__ void estinit_k(const float* __restrict__ pre_y, float* __restrict__ est_prev) {
    int i = blockIdx.x * 256 + threadIdx.x;   // n = 256*64
    est_prev[i] = pre_y[63 * 16384 + i];      // pre_y[-1]
}
__global__ void pack_enc_k(const float* __restrict__ pre_x, const float* __restrict__ pre_y,
                           u16* __restrict__ xy) {   // threads = 64*16*8*64
    int i = blockIdx.x * 256 + threadIdx.x;
    const int lane  = i & 63;
    const int kb    = (i >> 6) & 7;
    const int mtile = (i >> 9) & 15;
    const int t     = i >> 13;
    const int row   = mtile * 16 + (lane & 15);
    const int cb    = kb * 32 + (lane >> 4) * 8;
    u16* d = xy + (size_t)i * 8;
    #pragma unroll
    for (int j = 0; j < 8; ++j) {
        const int col = cb + j;
        const float v = (col < 192) ? pre_x[((size_t)t * 256 + row) * 192 + col]
                                    : pre_y[((size_t)t * 256 + row) * 64 + (col - 192)];
        d[j] = f2h(v);
    }
}
__global__ void pack_dec_k(const float* __restrict__ fx, u16* __restrict__ xd,
                           int total_threads) {      // threads = 48*16*6*64
    int i = blockIdx.x * 256 + threadIdx.x;
    if (i >= total_threads) return;
    const int lane  = i & 63;
    int rest = i >> 6;
    const int kb    = rest % 6;  rest /= 6;
    const int mtile = rest & 15;
    const int t     = rest >> 4;
    const int row   = mtile * 16 + (lane & 15);
    const int cb    = kb * 32 + (lane >> 4) * 8;
    u16* d = xd + ((((size_t)t * 16 + mtile) * 8 + kb) * 64 + lane) * 8;
    #pragma unroll
    for (int j = 0; j < 8; ++j)
        d[j] = f2h(fx[((size_t)t * 256 + row) * 192 + cb + j]);
}

extern "C" void kernel_launch(void* const* d_in, const int* in_sizes, int n_in,
                              void* d_out, int out_size, void* d_ws, size_t ws_size,
                              hipStream_t stream) {
    const float* pre_x  = (const float*)d_in[0];
    const float* pre_y  = (const float*)d_in[1];
    const float* fx     = (const float*)d_in[2];
    const float* w_ih_0 = (const float*)d_in[3];
    const float* w_hh_0 = (const float*)d_in[4];
    const float* b_ih_0 = (const float*)d_in[5];
    const float* b_hh_0 = (const float*)d_in[6];
    const float* w_ih_1 = (const float*)d_in[7];
    const float* w_hh_1 = (const float*)d_in[8];
    const float* b_ih_1 = (const float*)d_in[9];
    const float* b_hh_1 = (const float*)d_in[10];
    const float* fc_w1  = (const float*)d_in[11];
    const float* fc_b1  = (const float*)d_in[12];
    const float* fc_w2  = (const float*)d_in[13];
    const float* fc_b2  = (const float*)d_in[14];

    size_t off = 0;
    char* wsb = (char*)d_ws;
    auto alloc = [&](size_t bytes) -> void* {
        void* p = wsb + off;
        off += (bytes + 255) & ~(size_t)255;
        return p;
    };
    u16* wih0 = (u16*)alloc((size_t)4096 * 256 * 2);
    u16* whh0 = (u16*)alloc((size_t)4096 * 1024 * 2);
    u16* wih1 = (u16*)alloc((size_t)4096 * 1024 * 2);
    u16* whh1 = (u16*)alloc((size_t)4096 * 1024 * 2);
    u16* fcw1 = (u16*)alloc((size_t)1024 * 1024 * 2);
    u16* fcw2 = (u16*)alloc((size_t)64 * 1024 * 2);
    float* b0s = (float*)alloc(4096 * 4);
    float* b1s = (float*)alloc(4096 * 4);
    u16* xyenc = (u16*)alloc((size_t)64 * 256 * 256 * 2);
    u16* xdec  = (u16*)alloc((size_t)48 * 256 * 256 * 2);
    u16* h0a = (u16*)alloc((size_t)256 * 1024 * 2);
    u16* h0b = (u16*)alloc((size_t)256 * 1024 * 2);
    u16* h1a = (u16*)alloc((size_t)256 * 1024 * 2);
    u16* h1b = (u16*)alloc((size_t)256 * 1024 * 2);
    float* c0 = (float*)alloc((size_t)256 * 1024 * 4);
    float* c1 = (float*)alloc((size_t)256 * 1024 * 4);
    u16* ufc  = (u16*)alloc((size_t)256 * 1024 * 2);
    float* est0 = (float*)alloc((size_t)256 * 64 * 4);
    float* est1 = (float*)alloc((size_t)256 * 64 * 4);
    unsigned* bars = (unsigned*)alloc(4096);

    // --- setup ---
    hipMemsetAsync(bars, 0, 4096, stream);
    cvt_bfrag_k<<<512, 256, 0, stream>>>(w_ih_0, wih0, 256, 3, 1024, 16, 64 * 4 * 8 * 64);
    cvt_bfrag_k<<<2048, 256, 0, stream>>>(w_hh_0, whh0, 1024, 5, 1024, 16, 64 * 4 * 32 * 64);
    cvt_bfrag_k<<<2048, 256, 0, stream>>>(w_ih_1, wih1, 1024, 5, 1024, 16, 64 * 4 * 32 * 64);
    cvt_bfrag_k<<<2048, 256, 0, stream>>>(w_hh_1, whh1, 1024, 5, 1024, 16, 64 * 4 * 32 * 64);
    cvt_bfrag_k<<<512, 256, 0, stream>>>(fc_w1, fcw1, 1024, 5, 16, 64, 16 * 4 * 32 * 64);
    cvt_bfrag_k<<<32, 256, 0, stream>>>(fc_w2, fcw2, 1024, 5, 16, 0, 1 * 4 * 32 * 64);
    bias_k<<<16, 256, 0, stream>>>(b_ih_0, b_hh_0, b0s, 4096);
    bias_k<<<16, 256, 0, stream>>>(b_ih_1, b_hh_1, b1s, 4096);
    init_k<<<1024, 256, 0, stream>>>(h0a, h1a, c0, c1);
    estinit_k<<<64, 256, 0, stream>>>(pre_y, est0);
    pack_enc_k<<<2048, 256, 0, stream>>>(pre_x, pre_y, xyenc);
    pack_dec_k<<<1152, 256, 0, stream>>>(fx, xdec, 48 * 16 * 6 * 64);

    MegaP prm;
    prm.xyenc = xyenc;  prm.xdec = xdec;
    prm.wih0 = wih0;  prm.whh0 = whh0;  prm.wih1 = wih1;  prm.whh1 = whh1;
    prm.fcw1 = fcw1;  prm.fcw2 = fcw2;
    prm.b0s = b0s;  prm.b1s = b1s;  prm.fcb1 = fc_b1;  prm.fcb2 = fc_b2;
    prm.c0 = c0;  prm.c1 = c1;  prm.est0 = est0;  prm.est1 = est1;
    prm.out = (float*)d_out;
    prm.h0a = h0a;  prm.h0b = h0b;  prm.h1a = h1a;  prm.h1b = h1b;  prm.U = ufc;
    prm.bars = bars;

    // --- primary: persistent kernel, cooperative launch for co-residency ---
    void* kargs[] = { (void*)&prm };
    hipError_t ce = hipLaunchCooperativeKernel((const void*)mega_k, dim3(256), dim3(256),
                                               kargs, 0, stream);
    if (ce != hipSuccess) {
        // --- fallback: multi-launch ---
        for (int ph = 0; ph <= 64; ++ph)
            enc_phase_k<<<512, 256, 0, stream>>>(prm, ph);
        int cur = 0;
        for (int t = 0; t < 48; ++t) {
            fc1_fb_k<<<64, 256, 0, stream>>>(prm, cur);
            fc2_fb_k<<<16, 256, 0, stream>>>(prm, t);
            l0_fb_k<<<256, 256, 0, stream>>>(prm, t, cur);
            l1_fb_k<<<256, 256, 0, stream>>>(prm, cur);
            cur ^= 1;
        }
    }
}